// Round 22
// baseline (313.855 us; speedup 1.0000x reference)
//
#include <hip/hip_runtime.h>

#define N_NODES 100000
#define N_EDGES 800000
// IN=128, HID=256, OUT=128
#define SCAN_CHUNK 1024
#define SCAN_NB ((N_NODES + SCAN_CHUNK - 1) / SCAN_CHUNK)   // 98

typedef __attribute__((ext_vector_type(8))) _Float16 f16x8;
typedef __attribute__((ext_vector_type(4))) _Float16 f16x4;
typedef __attribute__((ext_vector_type(4))) float f32x4;

// ---------------- degree count (int atomics) ----------------
__global__ void count_int_k(const int* __restrict__ dst, int* __restrict__ cnt, int E) {
    int i = blockIdx.x * blockDim.x + threadIdx.x;
    if (i < E) atomicAdd(&cnt[dst[i]], 1);
}

// ---------------- scan pass 1 ----------------
__global__ __launch_bounds__(256) void scan1_k(const int* __restrict__ cnt,
                                               int* __restrict__ offs,
                                               int* __restrict__ bsums, int N) {
    __shared__ int s[256];
    int t = threadIdx.x;
    int base = blockIdx.x * SCAN_CHUNK + t * 4;
    int v0 = (base + 0 < N) ? cnt[base + 0] : 0;
    int v1 = (base + 1 < N) ? cnt[base + 1] : 0;
    int v2 = (base + 2 < N) ? cnt[base + 2] : 0;
    int v3 = (base + 3 < N) ? cnt[base + 3] : 0;
    int tsum = v0 + v1 + v2 + v3;
    s[t] = tsum;
    __syncthreads();
    for (int off = 1; off < 256; off <<= 1) {
        int val = (t >= off) ? s[t - off] : 0;
        __syncthreads();
        s[t] += val;
        __syncthreads();
    }
    int excl = s[t] - tsum;
    if (base + 0 < N) offs[base + 0] = excl;
    if (base + 1 < N) offs[base + 1] = excl + v0;
    if (base + 2 < N) offs[base + 2] = excl + v0 + v1;
    if (base + 3 < N) offs[base + 3] = excl + v0 + v1 + v2;
    if (t == 255) bsums[blockIdx.x] = s[255];
}

// ---------------- scan pass 2 ----------------
__global__ __launch_bounds__(256) void scan2_k(const int* __restrict__ bsums,
                                               int* __restrict__ boffs, int nb) {
    __shared__ int s[256];
    int t = threadIdx.x;
    int v = (t < nb) ? bsums[t] : 0;
    s[t] = v;
    __syncthreads();
    for (int off = 1; off < 256; off <<= 1) {
        int val = (t >= off) ? s[t - off] : 0;
        __syncthreads();
        s[t] += val;
        __syncthreads();
    }
    if (t < nb) boffs[t] = s[t] - v;
}

// ---------------- scan pass 3 ----------------
__global__ void scan3_k(int* __restrict__ offs, int* __restrict__ cursor,
                        const int* __restrict__ boffs, int N, int E) {
    int i = blockIdx.x * blockDim.x + threadIdx.x;
    if (i < N) {
        int v = offs[i] + boffs[i >> 10];
        offs[i] = v;
        cursor[i] = v;
    }
    if (i == 0) offs[N] = E;
}

// ---------------- bucket fill ----------------
__global__ void fill_k(const int* __restrict__ src, const int* __restrict__ dst,
                       int* __restrict__ cursor, int* __restrict__ perm, int E) {
    int e = blockIdx.x * blockDim.x + threadIdx.x;
    if (e < E) {
        int d = dst[e];
        int slot = atomicAdd(&cursor[d], 1);
        perm[slot] = src[e];
    }
}

// ---------------- bulk f32 -> f16 conversion (8 floats/thread) ----------------
__global__ __launch_bounds__(256) void cvt_f16_k(const float* __restrict__ in,
                                                 _Float16* __restrict__ outp, int n8) {
    int i = blockIdx.x * blockDim.x + threadIdx.x;
    if (i >= n8) return;
    const float4* p = (const float4*)in + (long long)i * 2;
    float4 v0 = p[0], v1 = p[1];
    f16x8 h;
    h[0] = (_Float16)v0.x; h[1] = (_Float16)v0.y;
    h[2] = (_Float16)v0.z; h[3] = (_Float16)v0.w;
    h[4] = (_Float16)v1.x; h[5] = (_Float16)v1.y;
    h[6] = (_Float16)v1.z; h[7] = (_Float16)v1.w;
    *(f16x8*)&outp[(long long)i * 8] = h;
}

// ---------------- gather-mean over f16 rows (f16x4/thread) -> f16 ----------------
__global__ __launch_bounds__(256) void aggmean_k(const _Float16* __restrict__ feat16,
                                                 const int* __restrict__ perm,
                                                 const int* __restrict__ offs,
                                                 _Float16* __restrict__ m16, int N) {
    int tid = threadIdx.x;
    int node = blockIdx.x * 8 + (tid >> 5);
    int q = tid & 31;                       // channels q*4..q*4+3
    if (node >= N) return;
    int beg = offs[node], end = offs[node + 1];
    float ax = 0, ay = 0, az = 0, aw = 0;
    float bx = 0, by = 0, bz = 0, bw = 0;
    int i = beg;
    for (; i + 1 < end; i += 2) {
        f16x4 v0 = *(const f16x4*)&feat16[(long long)perm[i] * 128 + q * 4];
        f16x4 v1 = *(const f16x4*)&feat16[(long long)perm[i + 1] * 128 + q * 4];
        ax += (float)v0[0]; ay += (float)v0[1]; az += (float)v0[2]; aw += (float)v0[3];
        bx += (float)v1[0]; by += (float)v1[1]; bz += (float)v1[2]; bw += (float)v1[3];
    }
    if (i < end) {
        f16x4 v0 = *(const f16x4*)&feat16[(long long)perm[i] * 128 + q * 4];
        ax += (float)v0[0]; ay += (float)v0[1]; az += (float)v0[2]; aw += (float)v0[3];
    }
    float rc = 1.0f / fmaxf((float)(end - beg), 1.0f);
    f16x4 v;
    v[0] = (_Float16)((ax + bx) * rc);
    v[1] = (_Float16)((ay + by) * rc);
    v[2] = (_Float16)((az + bz) * rc);
    v[3] = (_Float16)((aw + bw) * rc);
    *(f16x4*)&m16[(long long)node * 128 + q * 4] = v;
}

// ---------------- layer-2 agg fused epilogue: out = mean(g16) + r2(f16) + b2l ----------------
__global__ __launch_bounds__(256) void aggout_k(const _Float16* __restrict__ g16,
                                                const int* __restrict__ perm,
                                                const int* __restrict__ offs,
                                                const _Float16* __restrict__ r2h,
                                                const float* __restrict__ b2l,
                                                float* __restrict__ out, int N) {
    int tid = threadIdx.x;
    int node = blockIdx.x * 8 + (tid >> 5);
    int q = tid & 31;
    if (node >= N) return;
    int beg = offs[node], end = offs[node + 1];
    float ax = 0, ay = 0, az = 0, aw = 0;
    float bx = 0, by = 0, bz = 0, bw = 0;
    int i = beg;
    for (; i + 1 < end; i += 2) {
        f16x4 v0 = *(const f16x4*)&g16[(long long)perm[i] * 128 + q * 4];
        f16x4 v1 = *(const f16x4*)&g16[(long long)perm[i + 1] * 128 + q * 4];
        ax += (float)v0[0]; ay += (float)v0[1]; az += (float)v0[2]; aw += (float)v0[3];
        bx += (float)v1[0]; by += (float)v1[1]; bz += (float)v1[2]; bw += (float)v1[3];
    }
    if (i < end) {
        f16x4 v0 = *(const f16x4*)&g16[(long long)perm[i] * 128 + q * 4];
        ax += (float)v0[0]; ay += (float)v0[1]; az += (float)v0[2]; aw += (float)v0[3];
    }
    float rc = 1.0f / fmaxf((float)(end - beg), 1.0f);
    f16x4 rv = *(const f16x4*)&r2h[(long long)node * 128 + q * 4];
    float4 bv = ((const float4*)b2l)[q];
    float4 o;
    o.x = (ax + bx) * rc + (float)rv[0] + bv.x;
    o.y = (ay + by) * rc + (float)rv[1] + bv.y;
    o.z = (az + bz) * rc + (float)rv[2] + bv.z;
    o.w = (aw + bw) * rc + (float)rv[3] + bv.w;
    ((float4*)out)[(long long)node * 32 + q] = o;
}

// ---------------- async global->LDS, 16B/lane ----------------
__device__ inline void gload16(const void* g, void* l) {
    __builtin_amdgcn_global_load_lds(
        (const __attribute__((address_space(1))) unsigned int*)g,
        (__attribute__((address_space(3))) unsigned int*)l,
        16, 0, 0);
}

// ================= fp16 MFMA GEMM: A full-K in LDS (ONE stage), B direct from L2 ======
// C = A @ B^T fp16 (fp32 accumulate). 391 blocks, 1024 threads = 16 waves
// (4x4 wave grid, 64x64 per wave, acc[4][4] = 64 VGPR).
// A: full K=256 staged in one shot -> As 256 rows x 512 B = 128 KiB LDS,
//   ONE barrier-drain per block. Swizzle: chunk c (16 B) of row r at slot
//   c^(r&15) (low-4-bit XOR; frag reads = 16 consecutive slots = 2-way = free).
//   DMA: 2 rows/issue (lane r2=lane>>5, slot scs=lane&31, src chunk
//   scs^(row&15)); 8 issues/wave. Layer-1 source is per-lane selected
//   m16 (chunks 0..15) / x16 (chunks 16..31) -- global src addr is per-lane.
// B: NEVER staged -- fragments loaded global->VGPR per k-step (weights are
//   128 KB, L2-resident, shared by all blocks).
// LAYER 1: epilogue relu+bias -> h f16 (stride 256) via OH.
// LAYER 2: outputs g f16 (OH, cols 0..127) | r2 f16 (O1h, cols 128..255).
template <int LAYER>
__global__ __launch_bounds__(1024, 4) void gemm_mfma_k(
        const _Float16* __restrict__ Ap0, const _Float16* __restrict__ Ap1,
        const _Float16* __restrict__ Bp0, const _Float16* __restrict__ Bp1,
        const float* __restrict__ bias,
        _Float16* __restrict__ O1h,
        _Float16* __restrict__ OH, int N) {
    __shared__ _Float16 As[256 * 256];   // 128 KiB

    const int m0 = blockIdx.x * 256;
    const int tid = threadIdx.x;
    const int lane = tid & 63;
    const int wid = tid >> 6;           // 0..15
    const int wm = wid >> 2, wn = wid & 3;
    const int lr = lane & 15, lg = lane >> 4;

    // DMA lane geometry: 2 rows x 32 slots x 16 B = 1 KB per issue
    const int r2 = lane >> 5;          // row within 2-row segment
    const int scs = lane & 31;         // LDS slot this lane fills

    f32x4 acc[4][4];
#pragma unroll
    for (int i = 0; i < 4; i++)
#pragma unroll
        for (int j = 0; j < 4; j++) acc[i][j] = (f32x4)0.0f;

    // ---- STAGE: all of A (K=256) in one shot, 128 segs, 8 per wave ----
#pragma unroll
    for (int it = 0; it < 8; ++it) {
        int seg = wid * 8 + it;          // 0..127
        int row = seg * 2 + r2;          // 0..255
        int k32 = scs ^ (row & 15);      // pre-swizzled source chunk 0..31
        int gn = m0 + row;
        if (gn < N) {
            const _Float16* src;
            if constexpr (LAYER == 1)
                src = (k32 < 16) ? (Ap0 + (long long)gn * 128 + k32 * 8)
                                 : (Ap1 + (long long)gn * 128 + (k32 - 16) * 8);
            else
                src = Ap0 + (long long)gn * 256 + k32 * 8;
            gload16(src, &As[seg * 512]);
        }
    }
    __syncthreads();    // drain DMA: A ready (only barrier in the kernel body)

    // ---- COMPUTE: 8 k-steps of 32; B fragments direct from global (L2) ----
#pragma unroll
    for (int ks = 0; ks < 8; ++ks) {
        const int c = ks * 4 + lg;           // k-chunk 0..31
        const int kbase = ks * 32 + lg * 8;  // k element base 0..255
        f16x8 bf[4];
#pragma unroll
        for (int fc = 0; fc < 4; ++fc) {
            int c_ = wn * 64 + fc * 16 + lr;             // 0..255
            const _Float16* Bsrc;
            long long boff;
            if constexpr (LAYER == 1) {
                Bsrc = (kbase < 128) ? Bp0 : Bp1;        // W1l / W1r
                boff = (long long)c_ * 128 + (kbase & 127);
            } else {
                Bsrc = (c_ < 128) ? Bp0 : Bp1;           // W2l / W2r
                boff = (long long)(c_ & 127) * 256 + kbase;
            }
            bf[fc] = *(const f16x8*)(Bsrc + boff);
        }
#pragma unroll
        for (int fr = 0; fr < 4; ++fr) {
            int r_ = wm * 64 + fr * 16 + lr;             // 0..255
            f16x8 af = *(const f16x8*)&As[r_ * 256 + (c ^ (r_ & 15)) * 8];
#pragma unroll
            for (int fc = 0; fc < 4; ++fc)
                acc[fr][fc] = __builtin_amdgcn_mfma_f32_16x16x32_f16(af, bf[fc], acc[fr][fc], 0, 0, 0);
        }
    }

    // ---- epilogue: C/D map col=lane&15, row=(lane>>4)*4+reg ----
    if constexpr (LAYER == 1) {
#pragma unroll
        for (int fc = 0; fc < 4; ++fc) {
            int col = wn * 64 + fc * 16 + lr;       // 0..255
            float bv = bias[col];
#pragma unroll
            for (int fr = 0; fr < 4; ++fr) {
#pragma unroll
                for (int j = 0; j < 4; ++j) {
                    int row = m0 + wm * 64 + fr * 16 + lg * 4 + j;
                    if (row < N)
                        OH[(long long)row * 256 + col] =
                            (_Float16)fmaxf(acc[fr][fc][j] + bv, 0.0f);
                }
            }
        }
    } else {
#pragma unroll
        for (int fc = 0; fc < 4; ++fc) {
            int col = wn * 64 + fc * 16 + lr;       // 0..255
            _Float16* dp = (col < 128) ? OH : O1h;  // g | r2 (uniform per wn/fc)
            int dcol = col & 127;
#pragma unroll
            for (int fr = 0; fr < 4; ++fr) {
#pragma unroll
                for (int j = 0; j < 4; ++j) {
                    int row = m0 + wm * 64 + fr * 16 + lg * 4 + j;
                    if (row < N)
                        dp[(long long)row * 128 + dcol] = (_Float16)acc[fr][fc][j];
                }
            }
        }
    }
}

extern "C" void kernel_launch(void* const* d_in, const int* in_sizes, int n_in,
                              void* d_out, int out_size, void* d_ws, size_t ws_size,
                              hipStream_t stream) {
    const float* x   = (const float*)d_in[0];
    const int*   ei  = (const int*)d_in[1];     // [2, E]
    const float* W1l = (const float*)d_in[2];
    const float* b1l = (const float*)d_in[3];
    const float* W1r = (const float*)d_in[4];
    const float* W2l = (const float*)d_in[5];
    const float* b2l = (const float*)d_in[6];
    const float* W2r = (const float*)d_in[7];
    float* out = (float*)d_out;

    const int N = N_NODES, E = N_EDGES;
    const int* srcI = ei;
    const int* dstI = ei + E;

    char* ws = (char*)d_ws;
    size_t off = 0;
    auto alloc = [&](size_t bytes) {
        size_t o = off;
        off += (bytes + 511) & ~(size_t)511;
        return o;
    };
    size_t off_cnt   = alloc((size_t)N * 4);
    size_t off_offs  = alloc((size_t)(N + 1) * 4);
    size_t off_cur   = alloc((size_t)N * 4);
    size_t off_bsum  = alloc((size_t)SCAN_NB * 4);
    size_t off_boff  = alloc((size_t)SCAN_NB * 4);
    size_t off_perm  = alloc((size_t)E * 4);
    size_t off_x16   = alloc((size_t)N * 128 * 2);     // x f16
    size_t off_m16   = alloc((size_t)N * 128 * 2);     // mean f16
    size_t off_h16   = alloc((size_t)N * 256 * 2);     // h f16
    size_t off_g16   = alloc((size_t)N * 128 * 2);     // g f16
    size_t off_r2    = alloc((size_t)N * 128 * 2);     // r2 f16
    size_t off_w     = alloc((size_t)4 * 32768 * 2);   // 4 f16 weights
    int*      cntI = (int*)(ws + off_cnt);
    int*      offs = (int*)(ws + off_offs);
    int*      cur  = (int*)(ws + off_cur);
    int*      bsum = (int*)(ws + off_bsum);
    int*      boff = (int*)(ws + off_boff);
    int*      perm = (int*)(ws + off_perm);
    _Float16* x16  = (_Float16*)(ws + off_x16);
    _Float16* m16  = (_Float16*)(ws + off_m16);
    _Float16* h16  = (_Float16*)(ws + off_h16);
    _Float16* g16  = (_Float16*)(ws + off_g16);
    _Float16* r2h  = (_Float16*)(ws + off_r2);
    _Float16* wbuf = (_Float16*)(ws + off_w);
    const int WSZ = 32768;                             // 256*128 elems
    _Float16* w1l16 = wbuf;            _Float16* w1r16 = wbuf + WSZ;
    _Float16* w2l16 = wbuf + 2 * WSZ;  _Float16* w2r16 = wbuf + 3 * WSZ;

    // ---- CSR build ----
    (void)hipMemsetAsync(cntI, 0, (size_t)N * 4, stream);
    count_int_k<<<(E + 255) / 256, 256, 0, stream>>>(dstI, cntI, E);
    scan1_k<<<SCAN_NB, 256, 0, stream>>>(cntI, offs, bsum, N);
    scan2_k<<<1, 256, 0, stream>>>(bsum, boff, SCAN_NB);
    scan3_k<<<(N + 255) / 256, 256, 0, stream>>>(offs, cur, boff, N, E);
    fill_k<<<(E + 255) / 256, 256, 0, stream>>>(srcI, dstI, cur, perm, E);

    // ---- f16 conversions ----
    {
        int n8x = N * 16;                          // N*128/8
        cvt_f16_k<<<(n8x + 255) / 256, 256, 0, stream>>>(x, x16, n8x);
        int n8w = 32768 / 8;                       // 4096
        cvt_f16_k<<<(n8w + 255) / 256, 256, 0, stream>>>(W1l, w1l16, n8w);
        cvt_f16_k<<<(n8w + 255) / 256, 256, 0, stream>>>(W1r, w1r16, n8w);
        cvt_f16_k<<<(n8w + 255) / 256, 256, 0, stream>>>(W2l, w2l16, n8w);
        cvt_f16_k<<<(n8w + 255) / 256, 256, 0, stream>>>(W2r, w2r16, n8w);
    }

    // ---- layer 1 ----
    aggmean_k<<<(N + 7) / 8, 256, 0, stream>>>(x16, perm, offs, m16, N);
    {
        int nblk = (N + 255) / 256;   // 391
        gemm_mfma_k<1><<<nblk, 1024, 0, stream>>>(m16, x16, w1l16, w1r16,
                                                  b1l, nullptr, h16, N);
    }

    // ---- layer 2 ----
    {
        int nblk = (N + 255) / 256;
        gemm_mfma_k<2><<<nblk, 1024, 0, stream>>>(h16, h16, w2l16, w2r16,
                                                  nullptr, r2h, g16, N);
    }
    aggout_k<<<(N + 7) / 8, 256, 0, stream>>>(g16, perm, offs, r2h, b2l, out, N);
}

// Round 23
// 279.432 us; speedup vs baseline: 1.1232x; 1.1232x over previous
//
#include <hip/hip_runtime.h>

#define N_NODES 100000
#define N_EDGES 800000
// IN=128, HID=256, OUT=128
#define SCAN_CHUNK 1024
#define SCAN_NB ((N_NODES + SCAN_CHUNK - 1) / SCAN_CHUNK)   // 98

typedef __attribute__((ext_vector_type(8))) _Float16 f16x8;
typedef __attribute__((ext_vector_type(4))) _Float16 f16x4;
typedef __attribute__((ext_vector_type(4))) float f32x4;

// ---------------- degree count (int atomics) ----------------
__global__ void count_int_k(const int* __restrict__ dst, int* __restrict__ cnt, int E) {
    int i = blockIdx.x * blockDim.x + threadIdx.x;
    if (i < E) atomicAdd(&cnt[dst[i]], 1);
}

// ---------------- scan pass 1 ----------------
__global__ __launch_bounds__(256) void scan1_k(const int* __restrict__ cnt,
                                               int* __restrict__ offs,
                                               int* __restrict__ bsums, int N) {
    __shared__ int s[256];
    int t = threadIdx.x;
    int base = blockIdx.x * SCAN_CHUNK + t * 4;
    int v0 = (base + 0 < N) ? cnt[base + 0] : 0;
    int v1 = (base + 1 < N) ? cnt[base + 1] : 0;
    int v2 = (base + 2 < N) ? cnt[base + 2] : 0;
    int v3 = (base + 3 < N) ? cnt[base + 3] : 0;
    int tsum = v0 + v1 + v2 + v3;
    s[t] = tsum;
    __syncthreads();
    for (int off = 1; off < 256; off <<= 1) {
        int val = (t >= off) ? s[t - off] : 0;
        __syncthreads();
        s[t] += val;
        __syncthreads();
    }
    int excl = s[t] - tsum;
    if (base + 0 < N) offs[base + 0] = excl;
    if (base + 1 < N) offs[base + 1] = excl + v0;
    if (base + 2 < N) offs[base + 2] = excl + v0 + v1;
    if (base + 3 < N) offs[base + 3] = excl + v0 + v1 + v2;
    if (t == 255) bsums[blockIdx.x] = s[255];
}

// ---------------- scan pass 2 ----------------
__global__ __launch_bounds__(256) void scan2_k(const int* __restrict__ bsums,
                                               int* __restrict__ boffs, int nb) {
    __shared__ int s[256];
    int t = threadIdx.x;
    int v = (t < nb) ? bsums[t] : 0;
    s[t] = v;
    __syncthreads();
    for (int off = 1; off < 256; off <<= 1) {
        int val = (t >= off) ? s[t - off] : 0;
        __syncthreads();
        s[t] += val;
        __syncthreads();
    }
    if (t < nb) boffs[t] = s[t] - v;
}

// ---------------- scan pass 3 ----------------
__global__ void scan3_k(int* __restrict__ offs, int* __restrict__ cursor,
                        const int* __restrict__ boffs, int N, int E) {
    int i = blockIdx.x * blockDim.x + threadIdx.x;
    if (i < N) {
        int v = offs[i] + boffs[i >> 10];
        offs[i] = v;
        cursor[i] = v;
    }
    if (i == 0) offs[N] = E;
}

// ---------------- bucket fill ----------------
__global__ void fill_k(const int* __restrict__ src, const int* __restrict__ dst,
                       int* __restrict__ cursor, int* __restrict__ perm, int E) {
    int e = blockIdx.x * blockDim.x + threadIdx.x;
    if (e < E) {
        int d = dst[e];
        int slot = atomicAdd(&cursor[d], 1);
        perm[slot] = src[e];
    }
}

// ---------------- bulk f32 -> f16 conversion (8 floats/thread) ----------------
__global__ __launch_bounds__(256) void cvt_f16_k(const float* __restrict__ in,
                                                 _Float16* __restrict__ outp, int n8) {
    int i = blockIdx.x * blockDim.x + threadIdx.x;
    if (i >= n8) return;
    const float4* p = (const float4*)in + (long long)i * 2;
    float4 v0 = p[0], v1 = p[1];
    f16x8 h;
    h[0] = (_Float16)v0.x; h[1] = (_Float16)v0.y;
    h[2] = (_Float16)v0.z; h[3] = (_Float16)v0.w;
    h[4] = (_Float16)v1.x; h[5] = (_Float16)v1.y;
    h[6] = (_Float16)v1.z; h[7] = (_Float16)v1.w;
    *(f16x8*)&outp[(long long)i * 8] = h;
}

// ---------------- gather-mean, 16 lanes/node x f16x8 (16 B loads) ----------------
__global__ __launch_bounds__(256) void aggmean_k(const _Float16* __restrict__ feat16,
                                                 const int* __restrict__ perm,
                                                 const int* __restrict__ offs,
                                                 _Float16* __restrict__ m16, int N) {
    int tid = threadIdx.x;
    int node = blockIdx.x * 16 + (tid >> 4);
    int q = tid & 15;                       // channels q*8..q*8+7
    if (node >= N) return;
    int beg = offs[node], end = offs[node + 1];
    float a[8], b[8];
#pragma unroll
    for (int k = 0; k < 8; k++) { a[k] = 0.0f; b[k] = 0.0f; }
    int i = beg;
    for (; i + 1 < end; i += 2) {
        f16x8 v0 = *(const f16x8*)&feat16[(long long)perm[i] * 128 + q * 8];
        f16x8 v1 = *(const f16x8*)&feat16[(long long)perm[i + 1] * 128 + q * 8];
#pragma unroll
        for (int k = 0; k < 8; k++) { a[k] += (float)v0[k]; b[k] += (float)v1[k]; }
    }
    if (i < end) {
        f16x8 v0 = *(const f16x8*)&feat16[(long long)perm[i] * 128 + q * 8];
#pragma unroll
        for (int k = 0; k < 8; k++) a[k] += (float)v0[k];
    }
    float rc = 1.0f / fmaxf((float)(end - beg), 1.0f);
    f16x8 v;
#pragma unroll
    for (int k = 0; k < 8; k++) v[k] = (_Float16)((a[k] + b[k]) * rc);
    *(f16x8*)&m16[(long long)node * 128 + q * 8] = v;
}

// ---------------- layer-2 agg fused epilogue: out = mean(g16) + r2(f16) + b2l ----------------
__global__ __launch_bounds__(256) void aggout_k(const _Float16* __restrict__ g16,
                                                const int* __restrict__ perm,
                                                const int* __restrict__ offs,
                                                const _Float16* __restrict__ r2h,
                                                const float* __restrict__ b2l,
                                                float* __restrict__ out, int N) {
    int tid = threadIdx.x;
    int node = blockIdx.x * 16 + (tid >> 4);
    int q = tid & 15;                       // channels q*8..q*8+7
    if (node >= N) return;
    int beg = offs[node], end = offs[node + 1];
    float a[8], b[8];
#pragma unroll
    for (int k = 0; k < 8; k++) { a[k] = 0.0f; b[k] = 0.0f; }
    int i = beg;
    for (; i + 1 < end; i += 2) {
        f16x8 v0 = *(const f16x8*)&g16[(long long)perm[i] * 128 + q * 8];
        f16x8 v1 = *(const f16x8*)&g16[(long long)perm[i + 1] * 128 + q * 8];
#pragma unroll
        for (int k = 0; k < 8; k++) { a[k] += (float)v0[k]; b[k] += (float)v1[k]; }
    }
    if (i < end) {
        f16x8 v0 = *(const f16x8*)&g16[(long long)perm[i] * 128 + q * 8];
#pragma unroll
        for (int k = 0; k < 8; k++) a[k] += (float)v0[k];
    }
    float rc = 1.0f / fmaxf((float)(end - beg), 1.0f);
    f16x8 rv = *(const f16x8*)&r2h[(long long)node * 128 + q * 8];
    float4 bv0 = ((const float4*)b2l)[q * 2];
    float4 bv1 = ((const float4*)b2l)[q * 2 + 1];
    float4 o0, o1;
    o0.x = (a[0] + b[0]) * rc + (float)rv[0] + bv0.x;
    o0.y = (a[1] + b[1]) * rc + (float)rv[1] + bv0.y;
    o0.z = (a[2] + b[2]) * rc + (float)rv[2] + bv0.z;
    o0.w = (a[3] + b[3]) * rc + (float)rv[3] + bv0.w;
    o1.x = (a[4] + b[4]) * rc + (float)rv[4] + bv1.x;
    o1.y = (a[5] + b[5]) * rc + (float)rv[5] + bv1.y;
    o1.z = (a[6] + b[6]) * rc + (float)rv[6] + bv1.z;
    o1.w = (a[7] + b[7]) * rc + (float)rv[7] + bv1.w;
    ((float4*)out)[(long long)node * 32 + q * 2]     = o0;
    ((float4*)out)[(long long)node * 32 + q * 2 + 1] = o1;
}

// ---------------- async global->LDS, 16B/lane ----------------
__device__ inline void gload16(const void* g, void* l) {
    __builtin_amdgcn_global_load_lds(
        (const __attribute__((address_space(1))) unsigned int*)g,
        (__attribute__((address_space(3))) unsigned int*)l,
        16, 0, 0);
}

// ================= fp16 MFMA GEMM, 256x256 tile, 16 waves, BK=128, 2 STAGES ==========
// (r21 kernel, unchanged -- best measured GEMM: ~61 us/dispatch)
template <int LAYER>
__global__ __launch_bounds__(1024, 4) void gemm_mfma_k(
        const _Float16* __restrict__ Ap0, const _Float16* __restrict__ Ap1,
        const _Float16* __restrict__ Bp0, const _Float16* __restrict__ Bp1,
        const float* __restrict__ bias,
        _Float16* __restrict__ O1h,
        _Float16* __restrict__ OH, int N) {
    __shared__ _Float16 As[256 * 128];   // 64 KiB
    __shared__ _Float16 Bs[256 * 128];   // 64 KiB

    const int m0 = blockIdx.x * 256;
    const int tid = threadIdx.x;
    const int lane = tid & 63;
    const int wid = tid >> 6;           // 0..15
    const int wm = wid >> 2, wn = wid & 3;
    const int lr = lane & 15, lg = lane >> 4;

    // DMA lane geometry: 4 rows x 16 slots x 16 B = 1 KB per issue
    const int r4 = lane >> 4;          // row within 4-row segment
    const int scs = lane & 15;         // LDS slot this lane fills

    f32x4 acc[4][4];
#pragma unroll
    for (int i = 0; i < 4; i++)
#pragma unroll
        for (int j = 0; j < 4; j++) acc[i][j] = (f32x4)0.0f;

#pragma unroll
    for (int kt = 0; kt < 2; ++kt) {
        __syncthreads();    // previous stage's readers done
        // ---- STAGE kt: A 64 segs (4/wave), B 64 segs (4/wave) ----
        {
            const _Float16* Asrc;
            int aoffk;
            if constexpr (LAYER == 1) { Asrc = kt ? Ap1 : Ap0; aoffk = 0; }
            else                      { Asrc = Ap0;            aoffk = kt * 128; }
            constexpr int RSA = (LAYER == 1) ? 128 : 256;
#pragma unroll
            for (int it = 0; it < 4; ++it) {
                int seg = wid * 4 + it;          // 0..63
                int row = seg * 4 + r4;          // 0..255
                int k16 = scs ^ (row & 15);      // pre-swizzled source chunk
                int gn = m0 + row;
                if (gn < N)
                    gload16(Asrc + (long long)gn * RSA + aoffk + k16 * 8, &As[seg * 512]);
            }
#pragma unroll
            for (int it = 0; it < 4; ++it) {
                int seg = wid * 4 + it;          // 0..63
                int row = seg * 4 + r4;          // 0..255 (output col)
                int k16 = scs ^ (row & 15);
                const _Float16* Bsrc;
                long long boff;
                if constexpr (LAYER == 1) {
                    Bsrc = kt ? Bp1 : Bp0;                   // W1l / W1r, rows 0..255
                    boff = (long long)row * 128;
                } else {
                    Bsrc = (row < 128) ? Bp0 : Bp1;          // W2l / W2r
                    boff = (long long)(row & 127) * 256 + kt * 128;
                }
                gload16(Bsrc + boff + k16 * 8, &Bs[seg * 512]);
            }
        }
        __syncthreads();    // drain DMA: stage kt ready

        // ---- COMPUTE: 4 k-steps of 32 ----
#pragma unroll
        for (int ks = 0; ks < 4; ++ks) {
            const int c = ks * 4 + lg;           // k-chunk 0..15
            f16x8 bf[4];
#pragma unroll
            for (int fc = 0; fc < 4; ++fc) {
                int c_ = wn * 64 + fc * 16 + lr;             // 0..255
                bf[fc] = *(const f16x8*)&Bs[c_ * 128 + (c ^ (c_ & 15)) * 8];
            }
#pragma unroll
            for (int fr = 0; fr < 4; ++fr) {
                int r_ = wm * 64 + fr * 16 + lr;             // 0..255
                f16x8 af = *(const f16x8*)&As[r_ * 128 + (c ^ (r_ & 15)) * 8];
#pragma unroll
                for (int fc = 0; fc < 4; ++fc)
                    acc[fr][fc] = __builtin_amdgcn_mfma_f32_16x16x32_f16(af, bf[fc], acc[fr][fc], 0, 0, 0);
            }
        }
    }

    // ---- epilogue: C/D map col=lane&15, row=(lane>>4)*4+reg ----
    if constexpr (LAYER == 1) {
#pragma unroll
        for (int fc = 0; fc < 4; ++fc) {
            int col = wn * 64 + fc * 16 + lr;       // 0..255
            float bv = bias[col];
#pragma unroll
            for (int fr = 0; fr < 4; ++fr) {
#pragma unroll
                for (int j = 0; j < 4; ++j) {
                    int row = m0 + wm * 64 + fr * 16 + lg * 4 + j;
                    if (row < N)
                        OH[(long long)row * 256 + col] =
                            (_Float16)fmaxf(acc[fr][fc][j] + bv, 0.0f);
                }
            }
        }
    } else {
#pragma unroll
        for (int fc = 0; fc < 4; ++fc) {
            int col = wn * 64 + fc * 16 + lr;       // 0..255
            _Float16* dp = (col < 128) ? OH : O1h;  // g | r2 (uniform per wn)
            int dcol = col & 127;
#pragma unroll
            for (int fr = 0; fr < 4; ++fr) {
#pragma unroll
                for (int j = 0; j < 4; ++j) {
                    int row = m0 + wm * 64 + fr * 16 + lg * 4 + j;
                    if (row < N)
                        dp[(long long)row * 128 + dcol] = (_Float16)acc[fr][fc][j];
                }
            }
        }
    }
}

extern "C" void kernel_launch(void* const* d_in, const int* in_sizes, int n_in,
                              void* d_out, int out_size, void* d_ws, size_t ws_size,
                              hipStream_t stream) {
    const float* x   = (const float*)d_in[0];
    const int*   ei  = (const int*)d_in[1];     // [2, E]
    const float* W1l = (const float*)d_in[2];
    const float* b1l = (const float*)d_in[3];
    const float* W1r = (const float*)d_in[4];
    const float* W2l = (const float*)d_in[5];
    const float* b2l = (const float*)d_in[6];
    const float* W2r = (const float*)d_in[7];
    float* out = (float*)d_out;

    const int N = N_NODES, E = N_EDGES;
    const int* srcI = ei;
    const int* dstI = ei + E;

    char* ws = (char*)d_ws;
    size_t off = 0;
    auto alloc = [&](size_t bytes) {
        size_t o = off;
        off += (bytes + 511) & ~(size_t)511;
        return o;
    };
    size_t off_cnt   = alloc((size_t)N * 4);
    size_t off_offs  = alloc((size_t)(N + 1) * 4);
    size_t off_cur   = alloc((size_t)N * 4);
    size_t off_bsum  = alloc((size_t)SCAN_NB * 4);
    size_t off_boff  = alloc((size_t)SCAN_NB * 4);
    size_t off_perm  = alloc((size_t)E * 4);
    size_t off_x16   = alloc((size_t)N * 128 * 2);     // x f16
    size_t off_m16   = alloc((size_t)N * 128 * 2);     // mean f16
    size_t off_h16   = alloc((size_t)N * 256 * 2);     // h f16
    size_t off_g16   = alloc((size_t)N * 128 * 2);     // g f16
    size_t off_r2    = alloc((size_t)N * 128 * 2);     // r2 f16
    size_t off_w     = alloc((size_t)4 * 32768 * 2);   // 4 f16 weights
    int*      cntI = (int*)(ws + off_cnt);
    int*      offs = (int*)(ws + off_offs);
    int*      cur  = (int*)(ws + off_cur);
    int*      bsum = (int*)(ws + off_bsum);
    int*      boff = (int*)(ws + off_boff);
    int*      perm = (int*)(ws + off_perm);
    _Float16* x16  = (_Float16*)(ws + off_x16);
    _Float16* m16  = (_Float16*)(ws + off_m16);
    _Float16* h16  = (_Float16*)(ws + off_h16);
    _Float16* g16  = (_Float16*)(ws + off_g16);
    _Float16* r2h  = (_Float16*)(ws + off_r2);
    _Float16* wbuf = (_Float16*)(ws + off_w);
    const int WSZ = 32768;                             // 256*128 elems
    _Float16* w1l16 = wbuf;            _Float16* w1r16 = wbuf + WSZ;
    _Float16* w2l16 = wbuf + 2 * WSZ;  _Float16* w2r16 = wbuf + 3 * WSZ;

    // ---- CSR build ----
    (void)hipMemsetAsync(cntI, 0, (size_t)N * 4, stream);
    count_int_k<<<(E + 255) / 256, 256, 0, stream>>>(dstI, cntI, E);
    scan1_k<<<SCAN_NB, 256, 0, stream>>>(cntI, offs, bsum, N);
    scan2_k<<<1, 256, 0, stream>>>(bsum, boff, SCAN_NB);
    scan3_k<<<(N + 255) / 256, 256, 0, stream>>>(offs, cur, boff, N, E);
    fill_k<<<(E + 255) / 256, 256, 0, stream>>>(srcI, dstI, cur, perm, E);

    // ---- f16 conversions ----
    {
        int n8x = N * 16;                          // N*128/8
        cvt_f16_k<<<(n8x + 255) / 256, 256, 0, stream>>>(x, x16, n8x);
        int n8w = 32768 / 8;                       // 4096
        cvt_f16_k<<<(n8w + 255) / 256, 256, 0, stream>>>(W1l, w1l16, n8w);
        cvt_f16_k<<<(n8w + 255) / 256, 256, 0, stream>>>(W1r, w1r16, n8w);
        cvt_f16_k<<<(n8w + 255) / 256, 256, 0, stream>>>(W2l, w2l16, n8w);
        cvt_f16_k<<<(n8w + 255) / 256, 256, 0, stream>>>(W2r, w2r16, n8w);
    }

    // ---- layer 1 ----
    aggmean_k<<<(N + 15) / 16, 256, 0, stream>>>(x16, perm, offs, m16, N);
    {
        int nblk = (N + 255) / 256;   // 391
        gemm_mfma_k<1><<<nblk, 1024, 0, stream>>>(m16, x16, w1l16, w1r16,
                                                  b1l, nullptr, h16, N);
    }

    // ---- layer 2 ----
    {
        int nblk = (N + 255) / 256;
        gemm_mfma_k<2><<<nblk, 1024, 0, stream>>>(h16, h16, w2l16, w2r16,
                                                  nullptr, r2h, g16, N);
    }
    aggout_k<<<(N + 15) / 16, 256, 0, stream>>>(g16, perm, offs, r2h, b2l, out, N);
}

// Round 24
// 276.140 us; speedup vs baseline: 1.1366x; 1.0119x over previous
//
#include <hip/hip_runtime.h>

#define N_NODES 100000
#define N_EDGES 800000
#define SCAN_CHUNK 1024
#define SCAN_NB ((N_NODES + SCAN_CHUNK - 1) / SCAN_CHUNK)   // 98
#define ROWS_PER_BLK 391
#define TILES 25            // 25*16 = 400 >= 391

typedef __attribute__((ext_vector_type(8))) _Float16 f16x8;
typedef __attribute__((ext_vector_type(4))) _Float16 f16x4;
typedef __attribute__((ext_vector_type(4))) float f32x4;

// ---------------- degree count ----------------
__global__ void count_int_k(const int* __restrict__ dst, int* __restrict__ cnt, int E) {
    int i = blockIdx.x * blockDim.x + threadIdx.x;
    if (i < E) atomicAdd(&cnt[dst[i]], 1);
}

// ---------------- scan pass 1 ----------------
__global__ __launch_bounds__(256) void scan1_k(const int* __restrict__ cnt,
                                               int* __restrict__ offs,
                                               int* __restrict__ bsums, int N) {
    __shared__ int s[256];
    int t = threadIdx.x;
    int base = blockIdx.x * SCAN_CHUNK + t * 4;
    int v0 = (base + 0 < N) ? cnt[base + 0] : 0;
    int v1 = (base + 1 < N) ? cnt[base + 1] : 0;
    int v2 = (base + 2 < N) ? cnt[base + 2] : 0;
    int v3 = (base + 3 < N) ? cnt[base + 3] : 0;
    int tsum = v0 + v1 + v2 + v3;
    s[t] = tsum;
    __syncthreads();
    for (int off = 1; off < 256; off <<= 1) {
        int val = (t >= off) ? s[t - off] : 0;
        __syncthreads();
        s[t] += val;
        __syncthreads();
    }
    int excl = s[t] - tsum;
    if (base + 0 < N) offs[base + 0] = excl;
    if (base + 1 < N) offs[base + 1] = excl + v0;
    if (base + 2 < N) offs[base + 2] = excl + v0 + v1;
    if (base + 3 < N) offs[base + 3] = excl + v0 + v1 + v2;
    if (t == 255) bsums[blockIdx.x] = s[255];
}

// ---------------- scan pass 2 ----------------
__global__ __launch_bounds__(256) void scan2_k(const int* __restrict__ bsums,
                                               int* __restrict__ boffs, int nb) {
    __shared__ int s[256];
    int t = threadIdx.x;
    int v = (t < nb) ? bsums[t] : 0;
    s[t] = v;
    __syncthreads();
    for (int off = 1; off < 256; off <<= 1) {
        int val = (t >= off) ? s[t - off] : 0;
        __syncthreads();
        s[t] += val;
        __syncthreads();
    }
    if (t < nb) boffs[t] = s[t] - v;
}

// ---------------- scan pass 3 ----------------
__global__ void scan3_k(int* __restrict__ offs, int* __restrict__ cursor,
                        const int* __restrict__ boffs, int N, int E) {
    int i = blockIdx.x * blockDim.x + threadIdx.x;
    if (i < N) {
        int v = offs[i] + boffs[i >> 10];
        offs[i] = v;
        cursor[i] = v;
    }
    if (i == 0) offs[N] = E;
}

// ---------------- bucket fill ----------------
__global__ void fill_k(const int* __restrict__ src, const int* __restrict__ dst,
                       int* __restrict__ cursor, int* __restrict__ perm, int E) {
    int e = blockIdx.x * blockDim.x + threadIdx.x;
    if (e < E) {
        int d = dst[e];
        int slot = atomicAdd(&cursor[d], 1);
        perm[slot] = src[e];
    }
}

// ---------------- bulk f32 -> f16 ----------------
__global__ __launch_bounds__(256) void cvt_f16_k(const float* __restrict__ in,
                                                 _Float16* __restrict__ outp, int n8) {
    int i = blockIdx.x * blockDim.x + threadIdx.x;
    if (i >= n8) return;
    const float4* p = (const float4*)in + (long long)i * 2;
    float4 v0 = p[0], v1 = p[1];
    f16x8 h;
    h[0] = (_Float16)v0.x; h[1] = (_Float16)v0.y;
    h[2] = (_Float16)v0.z; h[3] = (_Float16)v0.w;
    h[4] = (_Float16)v1.x; h[5] = (_Float16)v1.y;
    h[6] = (_Float16)v1.z; h[7] = (_Float16)v1.w;
    *(f16x8*)&outp[(long long)i * 8] = h;
}

// ---------------- gather-mean, 16 lanes/node x f16x8 ----------------
__global__ __launch_bounds__(256) void aggmean_k(const _Float16* __restrict__ feat16,
                                                 const int* __restrict__ perm,
                                                 const int* __restrict__ offs,
                                                 _Float16* __restrict__ m16, int N) {
    int tid = threadIdx.x;
    int node = blockIdx.x * 16 + (tid >> 4);
    int q = tid & 15;
    if (node >= N) return;
    int beg = offs[node], end = offs[node + 1];
    float a[8], b[8];
#pragma unroll
    for (int k = 0; k < 8; k++) { a[k] = 0.0f; b[k] = 0.0f; }
    int i = beg;
    for (; i + 1 < end; i += 2) {
        f16x8 v0 = *(const f16x8*)&feat16[(long long)perm[i] * 128 + q * 8];
        f16x8 v1 = *(const f16x8*)&feat16[(long long)perm[i + 1] * 128 + q * 8];
#pragma unroll
        for (int k = 0; k < 8; k++) { a[k] += (float)v0[k]; b[k] += (float)v1[k]; }
    }
    if (i < end) {
        f16x8 v0 = *(const f16x8*)&feat16[(long long)perm[i] * 128 + q * 8];
#pragma unroll
        for (int k = 0; k < 8; k++) a[k] += (float)v0[k];
    }
    float rc = 1.0f / fmaxf((float)(end - beg), 1.0f);
    f16x8 v;
#pragma unroll
    for (int k = 0; k < 8; k++) v[k] = (_Float16)((a[k] + b[k]) * rc);
    *(f16x8*)&m16[(long long)node * 128 + q * 8] = v;
}

// ---------------- layer-2 agg fused epilogue ----------------
__global__ __launch_bounds__(256) void aggout_k(const _Float16* __restrict__ g16,
                                                const int* __restrict__ perm,
                                                const int* __restrict__ offs,
                                                const _Float16* __restrict__ r2h,
                                                const float* __restrict__ b2l,
                                                float* __restrict__ out, int N) {
    int tid = threadIdx.x;
    int node = blockIdx.x * 16 + (tid >> 4);
    int q = tid & 15;
    if (node >= N) return;
    int beg = offs[node], end = offs[node + 1];
    float a[8], b[8];
#pragma unroll
    for (int k = 0; k < 8; k++) { a[k] = 0.0f; b[k] = 0.0f; }
    int i = beg;
    for (; i + 1 < end; i += 2) {
        f16x8 v0 = *(const f16x8*)&g16[(long long)perm[i] * 128 + q * 8];
        f16x8 v1 = *(const f16x8*)&g16[(long long)perm[i + 1] * 128 + q * 8];
#pragma unroll
        for (int k = 0; k < 8; k++) { a[k] += (float)v0[k]; b[k] += (float)v1[k]; }
    }
    if (i < end) {
        f16x8 v0 = *(const f16x8*)&g16[(long long)perm[i] * 128 + q * 8];
#pragma unroll
        for (int k = 0; k < 8; k++) a[k] += (float)v0[k];
    }
    float rc = 1.0f / fmaxf((float)(end - beg), 1.0f);
    f16x8 rv = *(const f16x8*)&r2h[(long long)node * 128 + q * 8];
    float4 bv0 = ((const float4*)b2l)[q * 2];
    float4 bv1 = ((const float4*)b2l)[q * 2 + 1];
    float4 o0, o1;
    o0.x = (a[0] + b[0]) * rc + (float)rv[0] + bv0.x;
    o0.y = (a[1] + b[1]) * rc + (float)rv[1] + bv0.y;
    o0.z = (a[2] + b[2]) * rc + (float)rv[2] + bv0.z;
    o0.w = (a[3] + b[3]) * rc + (float)rv[3] + bv0.w;
    o1.x = (a[4] + b[4]) * rc + (float)rv[4] + bv1.x;
    o1.y = (a[5] + b[5]) * rc + (float)rv[5] + bv1.y;
    o1.z = (a[6] + b[6]) * rc + (float)rv[6] + bv1.z;
    o1.w = (a[7] + b[7]) * rc + (float)rv[7] + bv1.w;
    ((float4*)out)[(long long)node * 32 + q * 2]     = o0;
    ((float4*)out)[(long long)node * 32 + q * 2 + 1] = o1;
}

// ---------------- async global->LDS, 16B/lane ----------------
__device__ inline void gload16(const void* g, void* l) {
    __builtin_amdgcn_global_load_lds(
        (const __attribute__((address_space(1))) unsigned int*)g,
        (__attribute__((address_space(3))) unsigned int*)l,
        16, 0, 0);
}

// ========== resident-B stream-M fp16 MFMA GEMM ==========
// 256 blocks (1/CU), 512 threads = 8 waves. Block owns 391 consecutive rows.
// B (256 cols x 256 k, 128 KiB) loaded into LDS ONCE (only full drain).
// Then 25 pipelined A-tiles of 16 rows: STAGE(t+1) -> vmcnt(1) -> barrier ->
// COMPUTE(t) -> EPILOGUE(t) -> barrier. Counted vmcnt keeps next tile's loads
// in flight under compute (each wave issues exactly 1 gload16/tile).
// Swizzle: 16B chunk c of row/col r at slot c^(r&15) (2-way alias = free);
// DMA pre-swizzles the per-lane source chunk. Wave w covers cols w*32..+32:
// acc[2] (16 rows x 2x16 cols), 16 MFMA + 24 ds_read_b128 per tile.
// LAYER 1: A chunks<16 from m16 else x16; B chunks<16 from W1l else W1r;
//   epilogue relu+bias -> h f16 (OH, stride 256).
// LAYER 2: A = h16; B col<128 W2l else W2r; out g f16 (OH) | r2 f16 (O1h).
template <int LAYER>
__global__ __launch_bounds__(512, 1) void gemm_stream_k(
        const _Float16* __restrict__ Ap0, const _Float16* __restrict__ Ap1,
        const _Float16* __restrict__ Bp0, const _Float16* __restrict__ Bp1,
        const float* __restrict__ bias,
        _Float16* __restrict__ O1h,
        _Float16* __restrict__ OH, int N) {
    __shared__ _Float16 Bs[256 * 256];     // 128 KiB
    __shared__ _Float16 As2[2][16 * 256];  // 2 x 8 KiB

    const int mbase = blockIdx.x * ROWS_PER_BLK;
    const int rend = min(mbase + ROWS_PER_BLK, N);
    const int tid = threadIdx.x;
    const int lane = tid & 63;
    const int wid = tid >> 6;            // 0..7 (= wn: cols wid*32..+32)
    const int lr = lane & 15, lg = lane >> 4;
    const int r2 = lane >> 5;            // 0..1
    const int scs = lane & 31;           // chunk slot 0..31

    // ---- resident B load: wave w stages cols {2*(w*16+it)+r2}, 16 instr/wave ----
#pragma unroll
    for (int it = 0; it < 16; ++it) {
        int seg = wid * 16 + it;               // 0..127 (2 cols each)
        int col = seg * 2 + r2;                // 0..255
        int ck = scs ^ (col & 15);             // pre-swizzled source chunk
        const _Float16* src;
        if constexpr (LAYER == 1)
            src = (ck < 16) ? (Bp0 + (long long)col * 128 + ck * 8)
                            : (Bp1 + (long long)col * 128 + (ck - 16) * 8);
        else
            src = (col < 128) ? (Bp0 + (long long)col * 256 + ck * 8)
                              : (Bp1 + (long long)(col - 128) * 256 + ck * 8);
        gload16(src, &Bs[seg * 512]);
    }
    // ---- stage A tile 0 into buf 0 (1 instr/wave) ----
    {
        int lrow = wid * 2 + r2;               // 0..15
        int ck = scs ^ (lrow & 15);
        int gn = mbase + lrow;
        if (gn < N) {
            const _Float16* src;
            if constexpr (LAYER == 1)
                src = (ck < 16) ? (Ap0 + (long long)gn * 128 + ck * 8)
                                : (Ap1 + (long long)gn * 128 + (ck - 16) * 8);
            else
                src = Ap0 + (long long)gn * 256 + ck * 8;
            gload16(src, &As2[0][wid * 512]);
        }
    }
    asm volatile("s_waitcnt vmcnt(0)" ::: "memory");
    __builtin_amdgcn_s_barrier();

#pragma unroll 1
    for (int t = 0; t < TILES; ++t) {
        // ---- issue next tile's A stage (1 instr/wave) ----
        if (t + 1 < TILES) {
            int lrow = wid * 2 + r2;
            int ck = scs ^ (lrow & 15);
            int gn = mbase + (t + 1) * 16 + lrow;
            if (gn < N) {
                const _Float16* src;
                if constexpr (LAYER == 1)
                    src = (ck < 16) ? (Ap0 + (long long)gn * 128 + ck * 8)
                                    : (Ap1 + (long long)gn * 128 + (ck - 16) * 8);
                else
                    src = Ap0 + (long long)gn * 256 + ck * 8;
                gload16(src, &As2[(t + 1) & 1][wid * 512]);
            }
            asm volatile("s_waitcnt vmcnt(1)" ::: "memory");
        } else {
            asm volatile("s_waitcnt vmcnt(0)" ::: "memory");
        }
        __builtin_amdgcn_sched_barrier(0);
        __builtin_amdgcn_s_barrier();      // all waves' tile-t data in LDS

        // ---- compute tile t ----
        const _Float16* Ab = &As2[t & 1][0];
        f32x4 acc[2];
        acc[0] = (f32x4)0.0f;
        acc[1] = (f32x4)0.0f;
#pragma unroll
        for (int ks = 0; ks < 8; ++ks) {
            int c = ks * 4 + lg;               // k-chunk 0..31
            f16x8 af = *(const f16x8*)&Ab[lr * 256 + (c ^ lr) * 8];
#pragma unroll
            for (int fc = 0; fc < 2; ++fc) {
                int col = wid * 32 + fc * 16 + lr;
                f16x8 bf = *(const f16x8*)&Bs[col * 256 + (c ^ (col & 15)) * 8];
                acc[fc] = __builtin_amdgcn_mfma_f32_16x16x32_f16(af, bf, acc[fc], 0, 0, 0);
            }
        }

        // ---- epilogue tile t (global stores only) ----
#pragma unroll
        for (int fc = 0; fc < 2; ++fc) {
            int col = wid * 32 + fc * 16 + lr;
            if constexpr (LAYER == 1) {
                float bv = bias[col];
#pragma unroll
                for (int j = 0; j < 4; ++j) {
                    int row = mbase + t * 16 + lg * 4 + j;
                    if (row < rend)
                        OH[(long long)row * 256 + col] =
                            (_Float16)fmaxf(acc[fc][j] + bv, 0.0f);
                }
            } else {
                _Float16* dp = (col < 128) ? OH : O1h;
                int dcol = col & 127;
#pragma unroll
                for (int j = 0; j < 4; ++j) {
                    int row = mbase + t * 16 + lg * 4 + j;
                    if (row < rend)
                        dp[(long long)row * 128 + dcol] = (_Float16)acc[fc][j];
                }
            }
        }
        __builtin_amdgcn_s_barrier();      // readers done before buf reuse
    }
}

extern "C" void kernel_launch(void* const* d_in, const int* in_sizes, int n_in,
                              void* d_out, int out_size, void* d_ws, size_t ws_size,
                              hipStream_t stream) {
    const float* x   = (const float*)d_in[0];
    const int*   ei  = (const int*)d_in[1];     // [2, E]
    const float* W1l = (const float*)d_in[2];
    const float* b1l = (const float*)d_in[3];
    const float* W1r = (const float*)d_in[4];
    const float* W2l = (const float*)d_in[5];
    const float* b2l = (const float*)d_in[6];
    const float* W2r = (const float*)d_in[7];
    float* out = (float*)d_out;

    const int N = N_NODES, E = N_EDGES;
    const int* srcI = ei;
    const int* dstI = ei + E;

    char* ws = (char*)d_ws;
    size_t off = 0;
    auto alloc = [&](size_t bytes) {
        size_t o = off;
        off += (bytes + 511) & ~(size_t)511;
        return o;
    };
    size_t off_cnt   = alloc((size_t)N * 4);
    size_t off_offs  = alloc((size_t)(N + 1) * 4);
    size_t off_cur   = alloc((size_t)N * 4);
    size_t off_bsum  = alloc((size_t)SCAN_NB * 4);
    size_t off_boff  = alloc((size_t)SCAN_NB * 4);
    size_t off_perm  = alloc((size_t)E * 4);
    size_t off_x16   = alloc((size_t)N * 128 * 2);
    size_t off_m16   = alloc((size_t)N * 128 * 2);
    size_t off_h16   = alloc((size_t)N * 256 * 2);
    size_t off_g16   = alloc((size_t)N * 128 * 2);
    size_t off_r2    = alloc((size_t)N * 128 * 2);
    size_t off_w     = alloc((size_t)4 * 32768 * 2);
    int*      cntI = (int*)(ws + off_cnt);
    int*      offs = (int*)(ws + off_offs);
    int*      cur  = (int*)(ws + off_cur);
    int*      bsum = (int*)(ws + off_bsum);
    int*      boff = (int*)(ws + off_boff);
    int*      perm = (int*)(ws + off_perm);
    _Float16* x16  = (_Float16*)(ws + off_x16);
    _Float16* m16  = (_Float16*)(ws + off_m16);
    _Float16* h16  = (_Float16*)(ws + off_h16);
    _Float16* g16  = (_Float16*)(ws + off_g16);
    _Float16* r2h  = (_Float16*)(ws + off_r2);
    _Float16* wbuf = (_Float16*)(ws + off_w);
    const int WSZ = 32768;
    _Float16* w1l16 = wbuf;            _Float16* w1r16 = wbuf + WSZ;
    _Float16* w2l16 = wbuf + 2 * WSZ;  _Float16* w2r16 = wbuf + 3 * WSZ;

    // ---- CSR build ----
    (void)hipMemsetAsync(cntI, 0, (size_t)N * 4, stream);
    count_int_k<<<(E + 255) / 256, 256, 0, stream>>>(dstI, cntI, E);
    scan1_k<<<SCAN_NB, 256, 0, stream>>>(cntI, offs, bsum, N);
    scan2_k<<<1, 256, 0, stream>>>(bsum, boff, SCAN_NB);
    scan3_k<<<(N + 255) / 256, 256, 0, stream>>>(offs, cur, boff, N, E);
    fill_k<<<(E + 255) / 256, 256, 0, stream>>>(srcI, dstI, cur, perm, E);

    // ---- f16 conversions ----
    {
        int n8x = N * 16;
        cvt_f16_k<<<(n8x + 255) / 256, 256, 0, stream>>>(x, x16, n8x);
        int n8w = 32768 / 8;
        cvt_f16_k<<<(n8w + 255) / 256, 256, 0, stream>>>(W1l, w1l16, n8w);
        cvt_f16_k<<<(n8w + 255) / 256, 256, 0, stream>>>(W1r, w1r16, n8w);
        cvt_f16_k<<<(n8w + 255) / 256, 256, 0, stream>>>(W2l, w2l16, n8w);
        cvt_f16_k<<<(n8w + 255) / 256, 256, 0, stream>>>(W2r, w2r16, n8w);
    }

    // ---- layer 1 ----
    aggmean_k<<<(N + 15) / 16, 256, 0, stream>>>(x16, perm, offs, m16, N);
    gemm_stream_k<1><<<256, 512, 0, stream>>>(m16, x16, w1l16, w1r16,
                                              b1l, nullptr, h16, N);

    // ---- layer 2 ----
    gemm_stream_k<2><<<256, 512, 0, stream>>>(h16, h16, w2l16, w2r16,
                                              nullptr, r2h, g16, N);
    aggout_k<<<(N + 15) / 16, 256, 0, stream>>>(g16, perm, offs, r2h, b2l, out, N);
}

// Round 25
// 268.418 us; speedup vs baseline: 1.1693x; 1.0288x over previous
//
#include <hip/hip_runtime.h>

#define N_NODES 100000
#define N_EDGES 800000
#define SCAN_CHUNK 1024
#define SCAN_NB ((N_NODES + SCAN_CHUNK - 1) / SCAN_CHUNK)   // 98
#define ROWS_PER_BLK 391
#define TILES 25            // 25*16 = 400 >= 391

typedef __attribute__((ext_vector_type(8))) _Float16 f16x8;
typedef __attribute__((ext_vector_type(4))) _Float16 f16x4;
typedef __attribute__((ext_vector_type(4))) float f32x4;

// ---------------- degree count ----------------
__global__ void count_int_k(const int* __restrict__ dst, int* __restrict__ cnt, int E) {
    int i = blockIdx.x * blockDim.x + threadIdx.x;
    if (i < E) atomicAdd(&cnt[dst[i]], 1);
}

// ---------------- scan pass 1 ----------------
__global__ __launch_bounds__(256) void scan1_k(const int* __restrict__ cnt,
                                               int* __restrict__ offs,
                                               int* __restrict__ bsums, int N) {
    __shared__ int s[256];
    int t = threadIdx.x;
    int base = blockIdx.x * SCAN_CHUNK + t * 4;
    int v0 = (base + 0 < N) ? cnt[base + 0] : 0;
    int v1 = (base + 1 < N) ? cnt[base + 1] : 0;
    int v2 = (base + 2 < N) ? cnt[base + 2] : 0;
    int v3 = (base + 3 < N) ? cnt[base + 3] : 0;
    int tsum = v0 + v1 + v2 + v3;
    s[t] = tsum;
    __syncthreads();
    for (int off = 1; off < 256; off <<= 1) {
        int val = (t >= off) ? s[t - off] : 0;
        __syncthreads();
        s[t] += val;
        __syncthreads();
    }
    int excl = s[t] - tsum;
    if (base + 0 < N) offs[base + 0] = excl;
    if (base + 1 < N) offs[base + 1] = excl + v0;
    if (base + 2 < N) offs[base + 2] = excl + v0 + v1;
    if (base + 3 < N) offs[base + 3] = excl + v0 + v1 + v2;
    if (t == 255) bsums[blockIdx.x] = s[255];
}

// ---------------- scan pass 2 ----------------
__global__ __launch_bounds__(256) void scan2_k(const int* __restrict__ bsums,
                                               int* __restrict__ boffs, int nb) {
    __shared__ int s[256];
    int t = threadIdx.x;
    int v = (t < nb) ? bsums[t] : 0;
    s[t] = v;
    __syncthreads();
    for (int off = 1; off < 256; off <<= 1) {
        int val = (t >= off) ? s[t - off] : 0;
        __syncthreads();
        s[t] += val;
        __syncthreads();
    }
    if (t < nb) boffs[t] = s[t] - v;
}

// ---------------- scan pass 3 ----------------
__global__ void scan3_k(int* __restrict__ offs, int* __restrict__ cursor,
                        const int* __restrict__ boffs, int N, int E) {
    int i = blockIdx.x * blockDim.x + threadIdx.x;
    if (i < N) {
        int v = offs[i] + boffs[i >> 10];
        offs[i] = v;
        cursor[i] = v;
    }
    if (i == 0) offs[N] = E;
}

// ---------------- bucket fill ----------------
__global__ void fill_k(const int* __restrict__ src, const int* __restrict__ dst,
                       int* __restrict__ cursor, int* __restrict__ perm, int E) {
    int e = blockIdx.x * blockDim.x + threadIdx.x;
    if (e < E) {
        int d = dst[e];
        int slot = atomicAdd(&cursor[d], 1);
        perm[slot] = src[e];
    }
}

// ---------------- bulk f32 -> f16 ----------------
__global__ __launch_bounds__(256) void cvt_f16_k(const float* __restrict__ in,
                                                 _Float16* __restrict__ outp, int n8) {
    int i = blockIdx.x * blockDim.x + threadIdx.x;
    if (i >= n8) return;
    const float4* p = (const float4*)in + (long long)i * 2;
    float4 v0 = p[0], v1 = p[1];
    f16x8 h;
    h[0] = (_Float16)v0.x; h[1] = (_Float16)v0.y;
    h[2] = (_Float16)v0.z; h[3] = (_Float16)v0.w;
    h[4] = (_Float16)v1.x; h[5] = (_Float16)v1.y;
    h[6] = (_Float16)v1.z; h[7] = (_Float16)v1.w;
    *(f16x8*)&outp[(long long)i * 8] = h;
}

// ---------------- gather-mean, 16 lanes/node x f16x8 ----------------
__global__ __launch_bounds__(256) void aggmean_k(const _Float16* __restrict__ feat16,
                                                 const int* __restrict__ perm,
                                                 const int* __restrict__ offs,
                                                 _Float16* __restrict__ m16, int N) {
    int tid = threadIdx.x;
    int node = blockIdx.x * 16 + (tid >> 4);
    int q = tid & 15;
    if (node >= N) return;
    int beg = offs[node], end = offs[node + 1];
    float a[8], b[8];
#pragma unroll
    for (int k = 0; k < 8; k++) { a[k] = 0.0f; b[k] = 0.0f; }
    int i = beg;
    for (; i + 1 < end; i += 2) {
        f16x8 v0 = *(const f16x8*)&feat16[(long long)perm[i] * 128 + q * 8];
        f16x8 v1 = *(const f16x8*)&feat16[(long long)perm[i + 1] * 128 + q * 8];
#pragma unroll
        for (int k = 0; k < 8; k++) { a[k] += (float)v0[k]; b[k] += (float)v1[k]; }
    }
    if (i < end) {
        f16x8 v0 = *(const f16x8*)&feat16[(long long)perm[i] * 128 + q * 8];
#pragma unroll
        for (int k = 0; k < 8; k++) a[k] += (float)v0[k];
    }
    float rc = 1.0f / fmaxf((float)(end - beg), 1.0f);
    f16x8 v;
#pragma unroll
    for (int k = 0; k < 8; k++) v[k] = (_Float16)((a[k] + b[k]) * rc);
    *(f16x8*)&m16[(long long)node * 128 + q * 8] = v;
}

// ---------------- layer-2 agg fused epilogue ----------------
__global__ __launch_bounds__(256) void aggout_k(const _Float16* __restrict__ g16,
                                                const int* __restrict__ perm,
                                                const int* __restrict__ offs,
                                                const _Float16* __restrict__ r2h,
                                                const float* __restrict__ b2l,
                                                float* __restrict__ out, int N) {
    int tid = threadIdx.x;
    int node = blockIdx.x * 16 + (tid >> 4);
    int q = tid & 15;
    if (node >= N) return;
    int beg = offs[node], end = offs[node + 1];
    float a[8], b[8];
#pragma unroll
    for (int k = 0; k < 8; k++) { a[k] = 0.0f; b[k] = 0.0f; }
    int i = beg;
    for (; i + 1 < end; i += 2) {
        f16x8 v0 = *(const f16x8*)&g16[(long long)perm[i] * 128 + q * 8];
        f16x8 v1 = *(const f16x8*)&g16[(long long)perm[i + 1] * 128 + q * 8];
#pragma unroll
        for (int k = 0; k < 8; k++) { a[k] += (float)v0[k]; b[k] += (float)v1[k]; }
    }
    if (i < end) {
        f16x8 v0 = *(const f16x8*)&g16[(long long)perm[i] * 128 + q * 8];
#pragma unroll
        for (int k = 0; k < 8; k++) a[k] += (float)v0[k];
    }
    float rc = 1.0f / fmaxf((float)(end - beg), 1.0f);
    f16x8 rv = *(const f16x8*)&r2h[(long long)node * 128 + q * 8];
    float4 bv0 = ((const float4*)b2l)[q * 2];
    float4 bv1 = ((const float4*)b2l)[q * 2 + 1];
    float4 o0, o1;
    o0.x = (a[0] + b[0]) * rc + (float)rv[0] + bv0.x;
    o0.y = (a[1] + b[1]) * rc + (float)rv[1] + bv0.y;
    o0.z = (a[2] + b[2]) * rc + (float)rv[2] + bv0.z;
    o0.w = (a[3] + b[3]) * rc + (float)rv[3] + bv0.w;
    o1.x = (a[4] + b[4]) * rc + (float)rv[4] + bv1.x;
    o1.y = (a[5] + b[5]) * rc + (float)rv[5] + bv1.y;
    o1.z = (a[6] + b[6]) * rc + (float)rv[6] + bv1.z;
    o1.w = (a[7] + b[7]) * rc + (float)rv[7] + bv1.w;
    ((float4*)out)[(long long)node * 32 + q * 2]     = o0;
    ((float4*)out)[(long long)node * 32 + q * 2 + 1] = o1;
}

// ---------------- async global->LDS, 16B/lane ----------------
__device__ inline void gload16(const void* g, void* l) {
    __builtin_amdgcn_global_load_lds(
        (const __attribute__((address_space(1))) unsigned int*)g,
        (__attribute__((address_space(3))) unsigned int*)l,
        16, 0, 0);
}

// ========== resident-B stream-M fp16 MFMA GEMM, 2-deep A prefetch ==========
// 256 blocks (1/CU), 512 threads = 8 waves. Block owns 391 consecutive rows.
// B (256x256, 128 KiB) resident in LDS (loaded once). A streams in 16-row
// tiles through a 3-buffer ring with TWO tiles in flight: at tile t issue
// load(t+2), wait vmcnt(2) (load(t) done; t+1,t+2 flying ~2 tile-periods).
// Buffer safety: load(t+2) writes buf[(t-1)%3] whose readers finished
// before the end-of-iteration barrier of t-1. 1 gload16/wave/tile.
// Swizzle: 16B chunk c of row/col r at slot c^(r&15); DMA pre-swizzles.
// Wave w covers cols w*32..+32: acc[2], 16 MFMA + 24 ds_read per tile.
// LAYER 1: A = m16|x16 (per-lane chunk select), B = W1l|W1r (chunk select);
//   epilogue relu+bias -> h f16 (OH, stride 256).
// LAYER 2: A = h16; B col<128 W2l else W2r; out g f16 (OH) | r2 f16 (O1h).
template <int LAYER>
__global__ __launch_bounds__(512, 1) void gemm_stream_k(
        const _Float16* __restrict__ Ap0, const _Float16* __restrict__ Ap1,
        const _Float16* __restrict__ Bp0, const _Float16* __restrict__ Bp1,
        const float* __restrict__ bias,
        _Float16* __restrict__ O1h,
        _Float16* __restrict__ OH, int N) {
    __shared__ _Float16 Bs[256 * 256];     // 128 KiB
    __shared__ _Float16 As3[3][16 * 256];  // 3 x 8 KiB

    const int mbase = blockIdx.x * ROWS_PER_BLK;
    const int rend = min(mbase + ROWS_PER_BLK, N);
    const int tid = threadIdx.x;
    const int lane = tid & 63;
    const int wid = tid >> 6;            // 0..7 (cols wid*32..+32)
    const int lr = lane & 15, lg = lane >> 4;
    const int r2 = lane >> 5;            // 0..1
    const int scs = lane & 31;           // chunk slot 0..31

    // helper: issue A-tile stage for tile tt into buffer bi (1 instr/wave)
    auto STAGE_A = [&](int tt, int bi) {
        int lrow = wid * 2 + r2;               // 0..15
        int ck = scs ^ (lrow & 15);
        int gn = mbase + tt * 16 + lrow;
        if (gn < N) {
            const _Float16* src;
            if constexpr (LAYER == 1)
                src = (ck < 16) ? (Ap0 + (long long)gn * 128 + ck * 8)
                                : (Ap1 + (long long)gn * 128 + (ck - 16) * 8);
            else
                src = Ap0 + (long long)gn * 256 + ck * 8;
            gload16(src, &As3[bi][wid * 512]);
        }
    };

    // ---- resident B load: wave w stages cols {2*(w*16+it)+r2}, 16 instr/wave ----
#pragma unroll
    for (int it = 0; it < 16; ++it) {
        int seg = wid * 16 + it;               // 0..127 (2 cols each)
        int col = seg * 2 + r2;                // 0..255
        int ck = scs ^ (col & 15);             // pre-swizzled source chunk
        const _Float16* src;
        if constexpr (LAYER == 1)
            src = (ck < 16) ? (Bp0 + (long long)col * 128 + ck * 8)
                            : (Bp1 + (long long)col * 128 + (ck - 16) * 8);
        else
            src = (col < 128) ? (Bp0 + (long long)col * 256 + ck * 8)
                              : (Bp1 + (long long)(col - 128) * 256 + ck * 8);
        gload16(src, &Bs[seg * 512]);
    }
    // ---- prologue: stage tiles 0 and 1 ----
    STAGE_A(0, 0);
    STAGE_A(1, 1);
    // wait for B + tile 0 (tile 1 may stay in flight)
    asm volatile("s_waitcnt vmcnt(1)" ::: "memory");
    __builtin_amdgcn_s_barrier();

#pragma unroll 1
    for (int t = 0; t < TILES; ++t) {
        // ---- issue load(t+2); counted wait for load(t) ----
        if (t + 2 < TILES) {
            STAGE_A(t + 2, (t + 2) % 3);
            asm volatile("s_waitcnt vmcnt(2)" ::: "memory");
        } else if (t + 1 < TILES) {
            asm volatile("s_waitcnt vmcnt(1)" ::: "memory");
        } else {
            asm volatile("s_waitcnt vmcnt(0)" ::: "memory");
        }
        __builtin_amdgcn_sched_barrier(0);
        __builtin_amdgcn_s_barrier();      // all waves' tile-t data in LDS

        // ---- compute tile t ----
        const _Float16* Ab = &As3[t % 3][0];
        f32x4 acc[2];
        acc[0] = (f32x4)0.0f;
        acc[1] = (f32x4)0.0f;
#pragma unroll
        for (int ks = 0; ks < 8; ++ks) {
            int c = ks * 4 + lg;               // k-chunk 0..31
            f16x8 af = *(const f16x8*)&Ab[lr * 256 + (c ^ lr) * 8];
#pragma unroll
            for (int fc = 0; fc < 2; ++fc) {
                int col = wid * 32 + fc * 16 + lr;
                f16x8 bf = *(const f16x8*)&Bs[col * 256 + (c ^ (col & 15)) * 8];
                acc[fc] = __builtin_amdgcn_mfma_f32_16x16x32_f16(af, bf, acc[fc], 0, 0, 0);
            }
        }

        // ---- epilogue tile t (global stores only) ----
#pragma unroll
        for (int fc = 0; fc < 2; ++fc) {
            int col = wid * 32 + fc * 16 + lr;
            if constexpr (LAYER == 1) {
                float bv = bias[col];
#pragma unroll
                for (int j = 0; j < 4; ++j) {
                    int row = mbase + t * 16 + lg * 4 + j;
                    if (row < rend)
                        OH[(long long)row * 256 + col] =
                            (_Float16)fmaxf(acc[fc][j] + bv, 0.0f);
                }
            } else {
                _Float16* dp = (col < 128) ? OH : O1h;
                int dcol = col & 127;
#pragma unroll
                for (int j = 0; j < 4; ++j) {
                    int row = mbase + t * 16 + lg * 4 + j;
                    if (row < rend)
                        dp[(long long)row * 128 + dcol] = (_Float16)acc[fc][j];
                }
            }
        }
        __builtin_amdgcn_s_barrier();      // readers done before ring-buffer reuse
    }
}

extern "C" void kernel_launch(void* const* d_in, const int* in_sizes, int n_in,
                              void* d_out, int out_size, void* d_ws, size_t ws_size,
                              hipStream_t stream) {
    const float* x   = (const float*)d_in[0];
    const int*   ei  = (const int*)d_in[1];     // [2, E]
    const float* W1l = (const float*)d_in[2];
    const float* b1l = (const float*)d_in[3];
    const float* W1r = (const float*)d_in[4];
    const float* W2l = (const float*)d_in[5];
    const float* b2l = (const float*)d_in[6];
    const float* W2r = (const float*)d_in[7];
    float* out = (float*)d_out;

    const int N = N_NODES, E = N_EDGES;
    const int* srcI = ei;
    const int* dstI = ei + E;

    char* ws = (char*)d_ws;
    size_t off = 0;
    auto alloc = [&](size_t bytes) {
        size_t o = off;
        off += (bytes + 511) & ~(size_t)511;
        return o;
    };
    size_t off_cnt   = alloc((size_t)N * 4);
    size_t off_offs  = alloc((size_t)(N + 1) * 4);
    size_t off_cur   = alloc((size_t)N * 4);
    size_t off_bsum  = alloc((size_t)SCAN_NB * 4);
    size_t off_boff  = alloc((size_t)SCAN_NB * 4);
    size_t off_perm  = alloc((size_t)E * 4);
    size_t off_x16   = alloc((size_t)N * 128 * 2);
    size_t off_m16   = alloc((size_t)N * 128 * 2);
    size_t off_h16   = alloc((size_t)N * 256 * 2);
    size_t off_g16   = alloc((size_t)N * 128 * 2);
    size_t off_r2    = alloc((size_t)N * 128 * 2);
    size_t off_w     = alloc((size_t)4 * 32768 * 2);
    int*      cntI = (int*)(ws + off_cnt);
    int*      offs = (int*)(ws + off_offs);
    int*      cur  = (int*)(ws + off_cur);
    int*      bsum = (int*)(ws + off_bsum);
    int*      boff = (int*)(ws + off_boff);
    int*      perm = (int*)(ws + off_perm);
    _Float16* x16  = (_Float16*)(ws + off_x16);
    _Float16* m16  = (_Float16*)(ws + off_m16);
    _Float16* h16  = (_Float16*)(ws + off_h16);
    _Float16* g16  = (_Float16*)(ws + off_g16);
    _Float16* r2h  = (_Float16*)(ws + off_r2);
    _Float16* wbuf = (_Float16*)(ws + off_w);
    const int WSZ = 32768;
    _Float16* w1l16 = wbuf;            _Float16* w1r16 = wbuf + WSZ;
    _Float16* w2l16 = wbuf + 2 * WSZ;  _Float16* w2r16 = wbuf + 3 * WSZ;

    // ---- CSR build ----
    (void)hipMemsetAsync(cntI, 0, (size_t)N * 4, stream);
    count_int_k<<<(E + 255) / 256, 256, 0, stream>>>(dstI, cntI, E);
    scan1_k<<<SCAN_NB, 256, 0, stream>>>(cntI, offs, bsum, N);
    scan2_k<<<1, 256, 0, stream>>>(bsum, boff, SCAN_NB);
    scan3_k<<<(N + 255) / 256, 256, 0, stream>>>(offs, cur, boff, N, E);
    fill_k<<<(E + 255) / 256, 256, 0, stream>>>(srcI, dstI, cur, perm, E);

    // ---- f16 conversions ----
    {
        int n8x = N * 16;
        cvt_f16_k<<<(n8x + 255) / 256, 256, 0, stream>>>(x, x16, n8x);
        int n8w = 32768 / 8;
        cvt_f16_k<<<(n8w + 255) / 256, 256, 0, stream>>>(W1l, w1l16, n8w);
        cvt_f16_k<<<(n8w + 255) / 256, 256, 0, stream>>>(W1r, w1r16, n8w);
        cvt_f16_k<<<(n8w + 255) / 256, 256, 0, stream>>>(W2l, w2l16, n8w);
        cvt_f16_k<<<(n8w + 255) / 256, 256, 0, stream>>>(W2r, w2r16, n8w);
    }

    // ---- layer 1 ----
    aggmean_k<<<(N + 15) / 16, 256, 0, stream>>>(x16, perm, offs, m16, N);
    gemm_stream_k<1><<<256, 512, 0, stream>>>(m16, x16, w1l16, w1r16,
                                              b1l, nullptr, h16, N);

    // ---- layer 2 ----
    gemm_stream_k<2><<<256, 512, 0, stream>>>(h16, h16, w2l16, w2r16,
                                              nullptr, r2h, g16, N);
    aggout_k<<<(N + 15) / 16, 256, 0, stream>>>(g16, perm, offs, r2h, b2l, out, N);
}